// Round 1
// 609.834 us; speedup vs baseline: 1.1334x; 1.1334x over previous
//
#include <hip/hip_runtime.h>
#include <stdint.h>

// preds/targets: (8192, 64, 64) f32. N=8192 rows, C=4096 cols, k=N/2.
#define NROWS   8192
#define NCOLS   4096
#define KSEL    4096
#define THREADS 1024
#define NHIST   2048   // 11-bit first-level bins (was 256 8-bit: 18-way atomic storms)
#define NSUBP   3840   // worst-case p sub-bins: 8192/4 + 3*2048/4 = 3584 (+pad, mult of 4)
#define NSUBT   2816   // worst-case t sub-bins: 4096/4 + 3*2048/4 = 2560 (+pad, mult of 4)
#define TGT     4

// ---- LDS layout (72,792 B; x2 blocks = 145.6 KB <= 160 KB -> 2 blocks/CU) ----
// pD    @0      u32[8196] (8192 + 4 pad = 0xFFFFFFFF sentinels)
// pIdx  @32784  u16[8192]
// cnt   @49168  u32[3840]
// hist  @64528  u32[2048]  (single copy; re-used IN PLACE as combo after alloc)
// wtot  @72720  u32[16], sumAcc @72784 u64
// t-phase aliases (into pD region, written only after p-rank barrier):
// tD @0 u32[4100] (pad @4096..4099) | tPos @16400 u16[4096] | prArr @24592 u16[4096]

__device__ __forceinline__ uint32_t orderable(uint32_t b) {
    return b ^ ((b & 0x80000000u) ? 0xFFFFFFFFu : 0x80000000u);
}

__device__ __forceinline__ uint32_t wave_incl_scan(uint32_t v, int lane) {
#pragma unroll
    for (int off = 1; off < 64; off <<= 1) {
        uint32_t n = __shfl_up(v, off, 64);
        if (lane >= off) v += n;
    }
    return v;
}

// inclusive scan over lanes 0..15 of t16 (all waves redundantly); return the
// EXCLUSIVE prefix for index `wave` (wave is uniform per wave -> uniform shfl).
// Saves one __syncthreads vs the tid<16-then-rebroadcast pattern.
__device__ __forceinline__ uint32_t scan16_excl(uint32_t t16, int lane, int wave) {
#pragma unroll
    for (int off = 1; off < 16; off <<= 1) {
        uint32_t n = __shfl_up(t16, off, 64);
        if (lane >= off) t16 += n;
    }
    return wave ? __shfl(t16, wave - 1, 64) : 0u;
}

// hist[2048] counts -> in-place combo[b] = (subBase<<16) | nsplit
// (each thread touches only its own uint2, so in-place is race-free)
__device__ __forceinline__ void alloc_subbins(uint32_t* hist, uint32_t* wtot,
                                              int tid, int lane, int wave) {
    uint2 h = ((uint2*)hist)[tid];                     // bins 2*tid, 2*tid+1
    uint32_t ns0 = (h.x + TGT - 1) / TGT, ns1 = (h.y + TGT - 1) / TGT;
    uint32_t s2 = ns0 + ns1;
    uint32_t incl = wave_incl_scan(s2, lane);
    if (lane == 63) wtot[wave] = incl;
    __syncthreads();
    uint32_t wexcl = scan16_excl((lane < 16) ? wtot[lane] : 0u, lane, wave);
    uint32_t base = wexcl + incl - s2;
    ((uint2*)hist)[tid] = make_uint2((base << 16) | ns0, ((base + ns0) << 16) | ns1);
    __syncthreads();
}

// exclusive scan of cnt[0..4*n4) in place; after this cnt[s] = start of bin s
__device__ __forceinline__ void scan_cnt(uint32_t* cnt, uint32_t* wtot,
                                         int tid, int lane, int wave, int n4) {
    uint4 c4 = make_uint4(0, 0, 0, 0);
    bool act = tid < n4;
    if (act) c4 = ((uint4*)cnt)[tid];
    uint32_t s4 = c4.x + c4.y + c4.z + c4.w;
    uint32_t incl = wave_incl_scan(s4, lane);
    if (lane == 63) wtot[wave] = incl;
    __syncthreads();
    uint32_t wexcl = scan16_excl((lane < 16) ? wtot[lane] : 0u, lane, wave);
    if (act) {
        uint32_t base = wexcl + incl - s4;
        uint4 o; o.x = base; o.y = base + c4.x; o.z = o.y + c4.y; o.w = o.z + c4.z;
        ((uint4*)cnt)[tid] = o;
    }
    __syncthreads();
}

// first level: key>>21 (11 bits); second level: bits 20:13 scaled by nsplit
__device__ __forceinline__ uint32_t bin_of(uint32_t key, const uint32_t* combo) {
    uint32_t cb = combo[key >> 21];
    return (cb >> 16) + ((((key >> 13) & 255u) * (cb & 0xFFFFu)) >> 8);
}

__global__ __launch_bounds__(THREADS, 8)
void rank_ic_kernel(const float* __restrict__ preds,
                    const float* __restrict__ targets,
                    float* __restrict__ out) {
    const int bid = blockIdx.x;
    const int c = ((bid & 7) << 9) | (bid >> 3);  // XCD swizzle
    const int tid = threadIdx.x;
    const int lane = tid & 63;
    const int wave = tid >> 6;

    __shared__ __align__(16) uint8_t smem[72792];
    uint32_t* pD     = (uint32_t*)smem;
    uint16_t* pIdx   = (uint16_t*)(smem + 32784);
    uint32_t* cnt    = (uint32_t*)(smem + 49168);
    uint32_t* hist   = (uint32_t*)(smem + 64528);  // == combo after alloc
    uint32_t* wtot   = (uint32_t*)(smem + 72720);
    unsigned long long* sumAcc = (unsigned long long*)(smem + 72784);
    uint32_t* tD     = (uint32_t*)smem;            // aliases pD (post p-rank)
    uint16_t* tPos   = (uint16_t*)(smem + 16400);
    uint16_t* prArr  = (uint16_t*)(smem + 24592);

    // ---- p: load column, build keys (ascending d == descending p) ----
    uint32_t d[8];
#pragma unroll
    for (int j = 0; j < 8; ++j)
        d[j] = ~orderable(__float_as_uint(preds[(size_t)(j * THREADS + tid) * NCOLS + c]));

    // ---- init zero (b128) + sentinels ----
    const uint4 z4 = make_uint4(0, 0, 0, 0);
    if (tid < NSUBP / 4) ((uint4*)cnt)[tid] = z4;
    if (tid < NHIST / 4) ((uint4*)hist)[tid] = z4;
    if (tid < 4) pD[NROWS + tid] = 0xFFFFFFFFu;   // span-overrun pad (> any finite key)
    if (tid == 0) *sumAcc = 0ull;
    __syncthreads();

    // ---- p: 11-bit histogram, single copy (low same-address skew) ----
#pragma unroll
    for (int j = 0; j < 8; ++j) atomicAdd(&hist[d[j] >> 21], 1u);
    __syncthreads();

    alloc_subbins(hist, wtot, tid, lane, wave);

    // ---- p: count pass; atomic return value IS the within-bin sequence ----
    uint32_t pk[8];
#pragma unroll
    for (int j = 0; j < 8; ++j) {
        uint32_t s = bin_of(d[j], hist);
        uint32_t sq = atomicAdd(&cnt[s], 1u);
        pk[j] = s | (sq << 16);                  // s <= 3583 fits 12 bits
    }
    __syncthreads();

    scan_cnt(cnt, wtot, tid, lane, wave, NSUBP / 4);  // cnt[s] = bin start

    // ---- p: atomic-free scatter ----
#pragma unroll
    for (int j = 0; j < 8; ++j) {
        uint32_t s = pk[j] & 0xFFFu;
        uint32_t dst = cnt[s] + (pk[j] >> 16);
        pD[dst]   = d[j];
        pIdx[dst] = (uint16_t)(j * THREADS + tid);
    }
    __syncthreads();

    // ---- p: shared-span rank scan (positions tid*8 .. tid*8+7) ----
    uint32_t k8[8], idx8[8], rp[8];  // rp: low16 = rank, high16 = p_r
    {
        uint4 ka = ((const uint4*)pD)[tid * 2];
        uint4 kb = ((const uint4*)pD)[tid * 2 + 1];
        k8[0]=ka.x; k8[1]=ka.y; k8[2]=ka.z; k8[3]=ka.w;
        k8[4]=kb.x; k8[5]=kb.y; k8[6]=kb.z; k8[7]=kb.w;
        uint4 ib = ((const uint4*)pIdx)[tid];
        idx8[0]=ib.x&0xFFFFu; idx8[1]=ib.x>>16; idx8[2]=ib.y&0xFFFFu; idx8[3]=ib.y>>16;
        idx8[4]=ib.z&0xFFFFu; idx8[5]=ib.z>>16; idx8[6]=ib.w&0xFFFFu; idx8[7]=ib.w>>16;
    }
    {
        uint32_t A = cnt[bin_of(k8[0], hist)];
        uint32_t B = cnt[bin_of(k8[7], hist) + 1];
        uint32_t a0 = A & ~3u;
        uint32_t less[8] = {0,0,0,0,0,0,0,0}, eqc[8] = {0,0,0,0,0,0,0,0};
        for (uint32_t q = a0; q < B; q += 4) {
            uint4 kv = ((const uint4*)pD)[q >> 2];
#pragma unroll
            for (int j = 0; j < 8; ++j) {
                uint32_t kl = k8[j];
                less[j] += (kv.x < kl) + (kv.y < kl) + (kv.z < kl) + (kv.w < kl);
                eqc[j]  += (kv.x == kl) + (kv.y == kl) + (kv.z == kl) + (kv.w == kl);
            }
        }
#pragma unroll
        for (int j = 0; j < 8; ++j) {
            uint32_t i = a0 + less[j];           // first member of tie group (global)
            uint32_t eqb = 0;
            if (eqc[j] > 1) {                    // rare: true f32 ties
                for (uint32_t q = A; q < B; ++q)
                    if (pD[q] == k8[j]) eqb += ((uint32_t)pIdx[q] < idx8[j]);
            }
            uint32_t r = i + eqb;
            int jj = (int)(i + eqc[j] - 1); if (jj > KSEL - 1) jj = KSEL - 1;
            int pr = (KSEL - 1) - (int)i - jj + (int)r;  // verified tie rule (R1-R3)
            rp[j] = r | ((uint32_t)pr << 16);
        }
    }
    __syncthreads();  // pD/pIdx/cnt reads done; region reusable

    // ---- t prep: zero, pad, prArr, direct global gather of selected t ----
    if (tid < NSUBT / 4) ((uint4*)cnt)[tid] = z4;
    if (tid < NHIST / 4) ((uint4*)hist)[tid] = z4;
    if (tid < 4) tD[KSEL + tid] = 0xFFFFFFFFu;
    uint32_t tk[8] = {0,0,0,0,0,0,0,0};
#pragma unroll
    for (int j = 0; j < 8; ++j) {
        uint32_t r = rp[j] & 0xFFFFu;
        if (r < KSEL) {
            prArr[r] = (uint16_t)(rp[j] >> 16);
            tk[j] = orderable(__float_as_uint(targets[(size_t)idx8[j] * NCOLS + c]));
        }
    }
    __syncthreads();

    // ---- t: histogram (selected only) ----
#pragma unroll
    for (int j = 0; j < 8; ++j)
        if ((rp[j] & 0xFFFFu) < KSEL) atomicAdd(&hist[tk[j] >> 21], 1u);
    __syncthreads();

    alloc_subbins(hist, wtot, tid, lane, wave);

    uint32_t tpk[8];
#pragma unroll
    for (int j = 0; j < 8; ++j)
        if ((rp[j] & 0xFFFFu) < KSEL) {
            uint32_t s = bin_of(tk[j], hist);
            uint32_t sq = atomicAdd(&cnt[s], 1u);
            tpk[j] = s | (sq << 16);
        }
    __syncthreads();

    scan_cnt(cnt, wtot, tid, lane, wave, NSUBT / 4);

#pragma unroll
    for (int j = 0; j < 8; ++j) {
        uint32_t r = rp[j] & 0xFFFFu;
        if (r < KSEL) {
            uint32_t s = tpk[j] & 0xFFFu;
            uint32_t dst = cnt[s] + (tpk[j] >> 16);
            tD[dst]   = tk[j];
            tPos[dst] = (uint16_t)r;             // tie-break by p-position
        }
    }
    __syncthreads();

    // ---- t: shared-span rank scan + dot (positions tid*4 .. tid*4+3) ----
    long long S = 0;
    {
        uint4 kv4 = ((const uint4*)tD)[tid];
        uint2 pp  = ((const uint2*)tPos)[tid];
        uint32_t kk[4] = {kv4.x, kv4.y, kv4.z, kv4.w};
        uint32_t pq[4] = {pp.x & 0xFFFFu, pp.x >> 16, pp.y & 0xFFFFu, pp.y >> 16};
        uint32_t A = cnt[bin_of(kk[0], hist)];
        uint32_t B = cnt[bin_of(kk[3], hist) + 1];
        uint32_t a0 = A & ~3u;
        uint32_t less[4] = {0,0,0,0}, eqc[4] = {0,0,0,0};
        for (uint32_t q = a0; q < B; q += 4) {
            uint4 kv = ((const uint4*)tD)[q >> 2];
#pragma unroll
            for (int m = 0; m < 4; ++m) {
                uint32_t kl = kk[m];
                less[m] += (kv.x < kl) + (kv.y < kl) + (kv.z < kl) + (kv.w < kl);
                eqc[m]  += (kv.x == kl) + (kv.y == kl) + (kv.z == kl) + (kv.w == kl);
            }
        }
#pragma unroll
        for (int m = 0; m < 4; ++m) {
            uint32_t eqb = 0;
            if (eqc[m] > 1) {
                for (uint32_t q = A; q < B; ++q)
                    if (tD[q] == kk[m]) eqb += ((uint32_t)tPos[q] < pq[m]);
            }
            uint32_t tr = a0 + less[m] + eqb;
            S += (long long)prArr[pq[m]] * (long long)tr;
        }
    }

    // ---- reduce + epilogue (identical math to R1-R3 verified kernels) ----
#pragma unroll
    for (int off = 32; off > 0; off >>= 1)
        S += __shfl_down(S, off, 64);
    if (lane == 0) atomicAdd(sumAcc, (unsigned long long)S);
    __syncthreads();

    if (tid == 0) {
        double Sd = (double)(long long)(*sumAcc);
        double mean = (double)(KSEL - 1) * 0.5;
        double cov = Sd / (double)KSEL - mean * mean;
        double stdprod = (double)KSEL * (double)(KSEL + 1) / 12.0;
        out[c] = (float)(cov / (stdprod + 1e-8));
    }
}

extern "C" void kernel_launch(void* const* d_in, const int* in_sizes, int n_in,
                              void* d_out, int out_size, void* d_ws, size_t ws_size,
                              hipStream_t stream) {
    const float* preds   = (const float*)d_in[0];
    const float* targets = (const float*)d_in[1];
    float* out = (float*)d_out;
    hipLaunchKernelGGL(rank_ic_kernel, dim3(NCOLS), dim3(THREADS), 0, stream,
                       preds, targets, out);
}

// Round 2
// 608.886 us; speedup vs baseline: 1.1351x; 1.0016x over previous
//
#include <hip/hip_runtime.h>
#include <stdint.h>

// preds/targets: (8192, 64, 64) f32. N=8192 rows, C=4096 cols, k=N/2.
#define NROWS   8192
#define NCOLS   4096
#define KSEL    4096
#define THREADS 1024
#define NHIST   2048   // 11-bit first-level bins
#define NSUBP   3840   // worst-case p sub-bins: 8192/4 + 3*2048/4 = 3584 (+pad, mult of 4)
#define NSUBT   2816   // worst-case t sub-bins: 4096/4 + 3*2048/4 = 2560 (+pad, mult of 4)
#define TGT     4

// ---- LDS layout (72,792 B; x2 blocks = 145.6 KB <= 160 KB -> 2 blocks/CU) ----
// pD    @0      u32[8196] (8192 + 4 pad = 0xFFFFFFFF sentinels)
// pIdx  @32784  u16[8192]
// cnt   @49168  u32[3840]
// hist  @64528  u32[2048]  (single copy; re-used IN PLACE as combo after alloc)
// wtot  @72720  u32[16], sumAcc @72784 u64
// t-phase aliases (into pD region, written only after p-rank barrier):
// tD @0 u32[4100] (pad @4096..4099) | tPos @16400 u16[4096] | prArr @24592 u16[4096]

__device__ __forceinline__ uint32_t orderable(uint32_t b) {
    return b ^ ((b & 0x80000000u) ? 0xFFFFFFFFu : 0x80000000u);
}

__device__ __forceinline__ uint32_t wave_incl_scan(uint32_t v, int lane) {
#pragma unroll
    for (int off = 1; off < 64; off <<= 1) {
        uint32_t n = __shfl_up(v, off, 64);
        if (lane >= off) v += n;
    }
    return v;
}

// inclusive scan over lanes 0..15 of t16 (all waves redundantly); return the
// EXCLUSIVE prefix for index `wave` (wave is uniform per wave -> uniform shfl).
__device__ __forceinline__ uint32_t scan16_excl(uint32_t t16, int lane, int wave) {
#pragma unroll
    for (int off = 1; off < 16; off <<= 1) {
        uint32_t n = __shfl_up(t16, off, 64);
        if (lane >= off) t16 += n;
    }
    return wave ? __shfl(t16, wave - 1, 64) : 0u;
}

// hist[2048] counts -> in-place combo[b] = (subBase<<16) | nsplit
__device__ __forceinline__ void alloc_subbins(uint32_t* hist, uint32_t* wtot,
                                              int tid, int lane, int wave) {
    uint2 h = ((uint2*)hist)[tid];                     // bins 2*tid, 2*tid+1
    uint32_t ns0 = (h.x + TGT - 1) / TGT, ns1 = (h.y + TGT - 1) / TGT;
    uint32_t s2 = ns0 + ns1;
    uint32_t incl = wave_incl_scan(s2, lane);
    if (lane == 63) wtot[wave] = incl;
    __syncthreads();
    uint32_t wexcl = scan16_excl((lane < 16) ? wtot[lane] : 0u, lane, wave);
    uint32_t base = wexcl + incl - s2;
    ((uint2*)hist)[tid] = make_uint2((base << 16) | ns0, ((base + ns0) << 16) | ns1);
    __syncthreads();
}

// exclusive scan of cnt[0..4*n4) in place; after this cnt[s] = start of bin s
__device__ __forceinline__ void scan_cnt(uint32_t* cnt, uint32_t* wtot,
                                         int tid, int lane, int wave, int n4) {
    uint4 c4 = make_uint4(0, 0, 0, 0);
    bool act = tid < n4;
    if (act) c4 = ((uint4*)cnt)[tid];
    uint32_t s4 = c4.x + c4.y + c4.z + c4.w;
    uint32_t incl = wave_incl_scan(s4, lane);
    if (lane == 63) wtot[wave] = incl;
    __syncthreads();
    uint32_t wexcl = scan16_excl((lane < 16) ? wtot[lane] : 0u, lane, wave);
    if (act) {
        uint32_t base = wexcl + incl - s4;
        uint4 o; o.x = base; o.y = base + c4.x; o.z = o.y + c4.y; o.w = o.z + c4.z;
        ((uint4*)cnt)[tid] = o;
    }
    __syncthreads();
}

// first level: key>>21 (11 bits); second level: bits 20:13 scaled by nsplit
__device__ __forceinline__ uint32_t bin_of(uint32_t key, const uint32_t* combo) {
    uint32_t cb = combo[key >> 21];
    return (cb >> 16) + ((((key >> 13) & 255u) * (cb & 0xFFFFu)) >> 8);
}

__global__ __launch_bounds__(THREADS, 8)
void rank_ic_kernel(const float* __restrict__ preds,
                    const float* __restrict__ targets,
                    float* __restrict__ out) {
    const int bid = blockIdx.x;
    const int c = ((bid & 7) << 9) | (bid >> 3);  // XCD swizzle
    const int tid = threadIdx.x;
    const int lane = tid & 63;
    const int wave = tid >> 6;

    __shared__ __align__(16) uint8_t smem[72792];
    uint32_t* pD     = (uint32_t*)smem;
    uint16_t* pIdx   = (uint16_t*)(smem + 32784);
    uint32_t* cnt    = (uint32_t*)(smem + 49168);
    uint32_t* hist   = (uint32_t*)(smem + 64528);  // == combo after alloc
    uint32_t* wtot   = (uint32_t*)(smem + 72720);
    unsigned long long* sumAcc = (unsigned long long*)(smem + 72784);
    uint32_t* tD     = (uint32_t*)smem;            // aliases pD (post p-rank)
    uint16_t* tPos   = (uint16_t*)(smem + 16400);
    uint16_t* prArr  = (uint16_t*)(smem + 24592);

    // ---- p: load column, build keys (ascending d == descending p) ----
    uint32_t d[8];
#pragma unroll
    for (int j = 0; j < 8; ++j)
        d[j] = ~orderable(__float_as_uint(preds[(size_t)(j * THREADS + tid) * NCOLS + c]));

    // ---- init zero (b128) + sentinels ----
    const uint4 z4 = make_uint4(0, 0, 0, 0);
    if (tid < NSUBP / 4) ((uint4*)cnt)[tid] = z4;
    if (tid < NHIST / 4) ((uint4*)hist)[tid] = z4;
    if (tid < 4) pD[NROWS + tid] = 0xFFFFFFFFu;   // span-overrun pad (> any finite key)
    if (tid == 0) *sumAcc = 0ull;
    __syncthreads();

    // ---- p: 11-bit histogram, single copy (low same-address skew) ----
#pragma unroll
    for (int j = 0; j < 8; ++j) atomicAdd(&hist[d[j] >> 21], 1u);
    __syncthreads();

    alloc_subbins(hist, wtot, tid, lane, wave);

    // ---- p: count pass; atomic return value IS the within-bin sequence ----
    uint32_t pk[8];
#pragma unroll
    for (int j = 0; j < 8; ++j) {
        uint32_t s = bin_of(d[j], hist);
        uint32_t sq = atomicAdd(&cnt[s], 1u);
        pk[j] = s | (sq << 16);                  // s <= 3583 fits 12 bits
    }
    __syncthreads();

    scan_cnt(cnt, wtot, tid, lane, wave, NSUBP / 4);  // cnt[s] = bin start

    // ---- p: atomic-free scatter ----
#pragma unroll
    for (int j = 0; j < 8; ++j) {
        uint32_t s = pk[j] & 0xFFFu;
        uint32_t dst = cnt[s] + (pk[j] >> 16);
        pD[dst]   = d[j];
        pIdx[dst] = (uint16_t)(j * THREADS + tid);
    }
    __syncthreads();

    // ---- p: shared-span rank scan (positions tid*8 .. tid*8+7) ----
    // Skip test: sub-bins partition keys by bits >=13 and are key-ordered, so
    // every element's rank >= start of its sub-bin >= A (start of the octet's
    // lowest sub-bin). A >= KSEL => whole octet unselected (exact; a tie group
    // straddling the boundary lives in ONE sub-bin, forcing A < KSEL there).
    uint32_t k8[8], idx8[8] = {0,0,0,0,0,0,0,0}, rp[8];  // rp: low16=rank, hi16=p_r
    uint4 ka = ((const uint4*)pD)[tid * 2];
    k8[0]=ka.x; k8[1]=ka.y; k8[2]=ka.z; k8[3]=ka.w;
    uint32_t A = cnt[bin_of(k8[0], hist)];
    if (A >= KSEL) {
#pragma unroll
        for (int j = 0; j < 8; ++j) rp[j] = KSEL;   // unselected sentinel
    } else {
        uint4 kb = ((const uint4*)pD)[tid * 2 + 1];
        k8[4]=kb.x; k8[5]=kb.y; k8[6]=kb.z; k8[7]=kb.w;
        uint4 ib = ((const uint4*)pIdx)[tid];
        idx8[0]=ib.x&0xFFFFu; idx8[1]=ib.x>>16; idx8[2]=ib.y&0xFFFFu; idx8[3]=ib.y>>16;
        idx8[4]=ib.z&0xFFFFu; idx8[5]=ib.z>>16; idx8[6]=ib.w&0xFFFFu; idx8[7]=ib.w>>16;

        uint32_t B = cnt[bin_of(k8[7], hist) + 1];
        uint32_t a0 = A & ~3u;
        uint32_t less[8] = {0,0,0,0,0,0,0,0}, eqc[8] = {0,0,0,0,0,0,0,0};
        for (uint32_t q = a0; q < B; q += 4) {
            uint4 kv = ((const uint4*)pD)[q >> 2];
#pragma unroll
            for (int j = 0; j < 8; ++j) {
                uint32_t kl = k8[j];
                less[j] += (kv.x < kl) + (kv.y < kl) + (kv.z < kl) + (kv.w < kl);
                eqc[j]  += (kv.x == kl) + (kv.y == kl) + (kv.z == kl) + (kv.w == kl);
            }
        }
#pragma unroll
        for (int j = 0; j < 8; ++j) {
            uint32_t i = a0 + less[j];           // first member of tie group (global)
            uint32_t eqb = 0;
            if (eqc[j] > 1) {                    // rare: true f32 ties
                for (uint32_t q = A; q < B; ++q)
                    if (pD[q] == k8[j]) eqb += ((uint32_t)pIdx[q] < idx8[j]);
            }
            uint32_t r = i + eqb;
            int jj = (int)(i + eqc[j] - 1); if (jj > KSEL - 1) jj = KSEL - 1;
            int pr = (KSEL - 1) - (int)i - jj + (int)r;  // verified tie rule (R1-R3)
            rp[j] = r | ((uint32_t)pr << 16);
        }
    }
    __syncthreads();  // pD/pIdx/cnt reads done; region reusable

    // ---- t prep: zero, pad, prArr, direct global gather of selected t ----
    if (tid < NSUBT / 4) ((uint4*)cnt)[tid] = z4;
    if (tid < NHIST / 4) ((uint4*)hist)[tid] = z4;
    if (tid < 4) tD[KSEL + tid] = 0xFFFFFFFFu;
    uint32_t tk[8] = {0,0,0,0,0,0,0,0};
#pragma unroll
    for (int j = 0; j < 8; ++j) {
        uint32_t r = rp[j] & 0xFFFFu;
        if (r < KSEL) {
            prArr[r] = (uint16_t)(rp[j] >> 16);
            tk[j] = orderable(__float_as_uint(targets[(size_t)idx8[j] * NCOLS + c]));
        }
    }
    __syncthreads();

    // ---- t: histogram (selected only) ----
#pragma unroll
    for (int j = 0; j < 8; ++j)
        if ((rp[j] & 0xFFFFu) < KSEL) atomicAdd(&hist[tk[j] >> 21], 1u);
    __syncthreads();

    alloc_subbins(hist, wtot, tid, lane, wave);

    uint32_t tpk[8];
#pragma unroll
    for (int j = 0; j < 8; ++j)
        if ((rp[j] & 0xFFFFu) < KSEL) {
            uint32_t s = bin_of(tk[j], hist);
            uint32_t sq = atomicAdd(&cnt[s], 1u);
            tpk[j] = s | (sq << 16);
        }
    __syncthreads();

    scan_cnt(cnt, wtot, tid, lane, wave, NSUBT / 4);

#pragma unroll
    for (int j = 0; j < 8; ++j) {
        uint32_t r = rp[j] & 0xFFFFu;
        if (r < KSEL) {
            uint32_t s = tpk[j] & 0xFFFu;
            uint32_t dst = cnt[s] + (tpk[j] >> 16);
            tD[dst]   = tk[j];
            tPos[dst] = (uint16_t)r;             // tie-break by p-position
        }
    }
    __syncthreads();

    // ---- t: shared-span rank scan + dot (positions tid*4 .. tid*4+3) ----
    long long S = 0;
    {
        uint4 kv4 = ((const uint4*)tD)[tid];
        uint2 pp  = ((const uint2*)tPos)[tid];
        uint32_t kk[4] = {kv4.x, kv4.y, kv4.z, kv4.w};
        uint32_t pq[4] = {pp.x & 0xFFFFu, pp.x >> 16, pp.y & 0xFFFFu, pp.y >> 16};
        uint32_t A2 = cnt[bin_of(kk[0], hist)];
        uint32_t B2 = cnt[bin_of(kk[3], hist) + 1];
        uint32_t a0 = A2 & ~3u;
        uint32_t less[4] = {0,0,0,0}, eqc[4] = {0,0,0,0};
        for (uint32_t q = a0; q < B2; q += 4) {
            uint4 kv = ((const uint4*)tD)[q >> 2];
#pragma unroll
            for (int m = 0; m < 4; ++m) {
                uint32_t kl = kk[m];
                less[m] += (kv.x < kl) + (kv.y < kl) + (kv.z < kl) + (kv.w < kl);
                eqc[m]  += (kv.x == kl) + (kv.y == kl) + (kv.z == kl) + (kv.w == kl);
            }
        }
#pragma unroll
        for (int m = 0; m < 4; ++m) {
            uint32_t eqb = 0;
            if (eqc[m] > 1) {
                for (uint32_t q = A2; q < B2; ++q)
                    if (tD[q] == kk[m]) eqb += ((uint32_t)tPos[q] < pq[m]);
            }
            uint32_t tr = a0 + less[m] + eqb;
            S += (long long)prArr[pq[m]] * (long long)tr;
        }
    }

    // ---- reduce + epilogue (identical math to R1-R3 verified kernels) ----
#pragma unroll
    for (int off = 32; off > 0; off >>= 1)
        S += __shfl_down(S, off, 64);
    if (lane == 0) atomicAdd(sumAcc, (unsigned long long)S);
    __syncthreads();

    if (tid == 0) {
        double Sd = (double)(long long)(*sumAcc);
        double mean = (double)(KSEL - 1) * 0.5;
        double cov = Sd / (double)KSEL - mean * mean;
        double stdprod = (double)KSEL * (double)(KSEL + 1) / 12.0;
        out[c] = (float)(cov / (stdprod + 1e-8));
    }
}

extern "C" void kernel_launch(void* const* d_in, const int* in_sizes, int n_in,
                              void* d_out, int out_size, void* d_ws, size_t ws_size,
                              hipStream_t stream) {
    const float* preds   = (const float*)d_in[0];
    const float* targets = (const float*)d_in[1];
    float* out = (float*)d_out;
    hipLaunchKernelGGL(rank_ic_kernel, dim3(NCOLS), dim3(THREADS), 0, stream,
                       preds, targets, out);
}

// Round 3
// 545.781 us; speedup vs baseline: 1.2664x; 1.1156x over previous
//
#include <hip/hip_runtime.h>
#include <stdint.h>

// preds/targets: (8192, 64, 64) f32. N=8192 rows, C=4096 cols, k=N/2.
#define NROWS   8192
#define NCOLS   4096
#define KSEL    4096
#define THREADS 1024
#define NHIST   2048   // 11-bit first-level bins
#define NSUBP   3840   // worst-case p sub-bins: 8192/4 + 3*2048/4 = 3584 (+pad)
#define NSUBT   2816   // worst-case t sub-bins: 4096/4 + 3*2048/4 = 2560 (+pad)
#define TGT     4
#define NEX     127    // capacity of straddle-overflow queue (cnt spare tail)

// ---- LDS layout (72,800 B; x2 = 145.6 KB <= 160 KB -> 2 blocks/CU) ----
// pD @0 u32[8196] | pIdx @32784 u16[8192] | cnt @49168 u32[3840]
// hist @64528 u32[2048] | wtot @72720 u32[16] | sumAcc @72784 u64 | exCnt @72792 u32
// exQ = cnt[3586..3840): 127 (idx<<16|r, pr) pairs — free after scan_cnt (p span
// reads cnt only up to index 3584), and above t-phase's live cnt range (<=2816).
// t-phase aliases: tD @0 u32[4100] | tPos @16400 u16[4096] | prArr @24592 u16[4096]

__device__ __forceinline__ uint32_t orderable(uint32_t b) {
    return b ^ ((b & 0x80000000u) ? 0xFFFFFFFFu : 0x80000000u);
}

__device__ __forceinline__ uint32_t wave_incl_scan(uint32_t v, int lane) {
#pragma unroll
    for (int off = 1; off < 64; off <<= 1) {
        uint32_t n = __shfl_up(v, off, 64);
        if (lane >= off) v += n;
    }
    return v;
}

// inclusive scan over lanes 0..15 (all waves redundantly); returns EXCLUSIVE
// prefix for index `wave` (wave-uniform shfl).
__device__ __forceinline__ uint32_t scan16_excl(uint32_t t16, int lane, int wave) {
#pragma unroll
    for (int off = 1; off < 16; off <<= 1) {
        uint32_t n = __shfl_up(t16, off, 64);
        if (lane >= off) t16 += n;
    }
    return wave ? __shfl(t16, wave - 1, 64) : 0u;
}

// hist[2048] counts -> in-place combo[b] = (subBase<<16) | nsplit
__device__ __forceinline__ void alloc_subbins(uint32_t* hist, uint32_t* wtot,
                                              int tid, int lane, int wave) {
    uint2 h = ((uint2*)hist)[tid];
    uint32_t ns0 = (h.x + TGT - 1) / TGT, ns1 = (h.y + TGT - 1) / TGT;
    uint32_t s2 = ns0 + ns1;
    uint32_t incl = wave_incl_scan(s2, lane);
    if (lane == 63) wtot[wave] = incl;
    __syncthreads();
    uint32_t wexcl = scan16_excl((lane < 16) ? wtot[lane] : 0u, lane, wave);
    uint32_t base = wexcl + incl - s2;
    ((uint2*)hist)[tid] = make_uint2((base << 16) | ns0, ((base + ns0) << 16) | ns1);
    __syncthreads();
}

// exclusive scan of cnt[0..4*n4) in place; after this cnt[s] = start of bin s
__device__ __forceinline__ void scan_cnt(uint32_t* cnt, uint32_t* wtot,
                                         int tid, int lane, int wave, int n4) {
    uint4 c4 = make_uint4(0, 0, 0, 0);
    bool act = tid < n4;
    if (act) c4 = ((uint4*)cnt)[tid];
    uint32_t s4 = c4.x + c4.y + c4.z + c4.w;
    uint32_t incl = wave_incl_scan(s4, lane);
    if (lane == 63) wtot[wave] = incl;
    __syncthreads();
    uint32_t wexcl = scan16_excl((lane < 16) ? wtot[lane] : 0u, lane, wave);
    if (act) {
        uint32_t base = wexcl + incl - s4;
        uint4 o; o.x = base; o.y = base + c4.x; o.z = o.y + c4.y; o.w = o.z + c4.z;
        ((uint4*)cnt)[tid] = o;
    }
    __syncthreads();
}

// first level: key>>21 (11 bits); second level: bits 20:13 scaled by nsplit
__device__ __forceinline__ uint32_t bin_of(uint32_t key, const uint32_t* combo) {
    uint32_t cb = combo[key >> 21];
    return (cb >> 16) + ((((key >> 13) & 255u) * (cb & 0xFFFFu)) >> 8);
}

__global__ __launch_bounds__(THREADS, 8)
void rank_ic_kernel(const float* __restrict__ preds,
                    const float* __restrict__ targets,
                    float* __restrict__ out) {
    const int bid = blockIdx.x;
    const int c = ((bid & 7) << 9) | (bid >> 3);  // XCD swizzle
    const int tid = threadIdx.x;
    const int lane = tid & 63;
    const int wave = tid >> 6;

    __shared__ __align__(16) uint8_t smem[72800];
    uint32_t* pD     = (uint32_t*)smem;
    uint16_t* pIdx   = (uint16_t*)(smem + 32784);
    uint32_t* cnt    = (uint32_t*)(smem + 49168);
    uint32_t* hist   = (uint32_t*)(smem + 64528);  // == combo after alloc
    uint32_t* wtot   = (uint32_t*)(smem + 72720);
    unsigned long long* sumAcc = (unsigned long long*)(smem + 72784);
    uint32_t* exCnt  = (uint32_t*)(smem + 72792);
    uint32_t* exQ    = cnt + 3586;                 // 254 u32 spare (see layout)
    uint32_t* tD     = (uint32_t*)smem;            // aliases pD (post p-rank)
    uint16_t* tPos   = (uint16_t*)(smem + 16400);
    uint16_t* prArr  = (uint16_t*)(smem + 24592);

    // ---- p: load column, build keys (ascending d == descending p) ----
    uint32_t d[8];
#pragma unroll
    for (int j = 0; j < 8; ++j)
        d[j] = ~orderable(__float_as_uint(preds[(size_t)(j * THREADS + tid) * NCOLS + c]));

    // ---- init zero (b128) + sentinels ----
    const uint4 z4 = make_uint4(0, 0, 0, 0);
    if (tid < NSUBP / 4) ((uint4*)cnt)[tid] = z4;
    if (tid < NHIST / 4) ((uint4*)hist)[tid] = z4;
    if (tid < 4) pD[NROWS + tid] = 0xFFFFFFFFu;   // span-overrun pad
    if (tid == 0) { *sumAcc = 0ull; *exCnt = 0u; }
    __syncthreads();

    // ---- p: 11-bit histogram ----
#pragma unroll
    for (int j = 0; j < 8; ++j) atomicAdd(&hist[d[j] >> 21], 1u);
    __syncthreads();

    alloc_subbins(hist, wtot, tid, lane, wave);

    // ---- p: count pass; atomic return value IS the within-bin sequence ----
    uint32_t pk[8];
#pragma unroll
    for (int j = 0; j < 8; ++j) {
        uint32_t s = bin_of(d[j], hist);
        uint32_t sq = atomicAdd(&cnt[s], 1u);
        pk[j] = s | (sq << 16);
    }
    __syncthreads();

    scan_cnt(cnt, wtot, tid, lane, wave, NSUBP / 4);  // cnt[s] = bin start

    // ---- p: atomic-free scatter ----
#pragma unroll
    for (int j = 0; j < 8; ++j) {
        uint32_t s = pk[j] & 0xFFFu;
        uint32_t dst = cnt[s] + (pk[j] >> 16);
        pD[dst]   = d[j];
        pIdx[dst] = (uint16_t)(j * THREADS + tid);
    }
    __syncthreads();

    // ---- p span, LOW: positions tid*4..+3 (all of [0,4096), every wave busy).
    // Early-issue the t gather (position<4096 ~ selected) to hide VMEM latency
    // under the span compute; values drain at the phase-end barrier.
    uint32_t rp4[4];          // r | pr<<16
    uint32_t tk4[4];
    float tv[4];
    {
        uint4 kq = ((const uint4*)pD)[tid];
        uint32_t k4[4] = {kq.x, kq.y, kq.z, kq.w};
        uint2 iq = ((const uint2*)pIdx)[tid];
        uint32_t i4[4] = {iq.x & 0xFFFFu, iq.x >> 16, iq.y & 0xFFFFu, iq.y >> 16};
#pragma unroll
        for (int j = 0; j < 4; ++j)
            tv[j] = targets[(size_t)i4[j] * NCOLS + c];   // early gather

        uint32_t A = cnt[bin_of(k4[0], hist)];
        uint32_t B = cnt[bin_of(k4[3], hist) + 1];
        uint32_t a0 = A & ~3u;
        uint32_t less[4] = {0,0,0,0}, eqc[4] = {0,0,0,0};
        for (uint32_t q = a0; q < B; q += 4) {
            uint4 kv = ((const uint4*)pD)[q >> 2];
#pragma unroll
            for (int m = 0; m < 4; ++m) {
                uint32_t kl = k4[m];
                less[m] += (kv.x < kl) + (kv.y < kl) + (kv.z < kl) + (kv.w < kl);
                eqc[m]  += (kv.x == kl) + (kv.y == kl) + (kv.z == kl) + (kv.w == kl);
            }
        }
#pragma unroll
        for (int m = 0; m < 4; ++m) {
            uint32_t i = a0 + less[m];
            uint32_t eqb = 0;
            if (eqc[m] > 1) {                    // rare: true f32 ties
                for (uint32_t q = A; q < B; ++q)
                    if (pD[q] == k4[m]) eqb += ((uint32_t)pIdx[q] < i4[m]);
            }
            uint32_t r = i + eqb;
            int jj = (int)(i + eqc[m] - 1); if (jj > KSEL - 1) jj = KSEL - 1;
            int pr = (KSEL - 1) - (int)i - jj + (int)r;  // verified tie rule
            rp4[m] = r | ((uint32_t)pr << 16);
        }
    }

    // ---- p span, HIGH: positions 4096+tid*4..+3. Skip test: rank >= sub-bin
    // start >= A; A >= KSEL => all 4 unselected (ties live in one sub-bin, so a
    // straddling tie group forces A < KSEL). Active for ~1-6 threads; selected
    // results go to exQ and are adopted as a 5th t-slot below.
    {
        uint4 kq = ((const uint4*)pD)[1024 + tid];
        uint32_t A = cnt[bin_of(kq.x, hist)];
        if (A < KSEL) {
            uint32_t k4[4] = {kq.x, kq.y, kq.z, kq.w};
            uint2 iq = ((const uint2*)pIdx)[1024 + tid];
            uint32_t i4[4] = {iq.x & 0xFFFFu, iq.x >> 16, iq.y & 0xFFFFu, iq.y >> 16};
            uint32_t B = cnt[bin_of(k4[3], hist) + 1];
            uint32_t a0 = A & ~3u;
            uint32_t less[4] = {0,0,0,0}, eqc[4] = {0,0,0,0};
            for (uint32_t q = a0; q < B; q += 4) {
                uint4 kv = ((const uint4*)pD)[q >> 2];
#pragma unroll
                for (int m = 0; m < 4; ++m) {
                    uint32_t kl = k4[m];
                    less[m] += (kv.x < kl) + (kv.y < kl) + (kv.z < kl) + (kv.w < kl);
                    eqc[m]  += (kv.x == kl) + (kv.y == kl) + (kv.z == kl) + (kv.w == kl);
                }
            }
#pragma unroll
            for (int m = 0; m < 4; ++m) {
                uint32_t i = a0 + less[m];
                uint32_t eqb = 0;
                if (eqc[m] > 1) {
                    for (uint32_t q = A; q < B; ++q)
                        if (pD[q] == k4[m]) eqb += ((uint32_t)pIdx[q] < i4[m]);
                }
                uint32_t r = i + eqb;
                if (r < KSEL) {
                    int jj = (int)(i + eqc[m] - 1); if (jj > KSEL - 1) jj = KSEL - 1;
                    int pr = (KSEL - 1) - (int)i - jj + (int)r;
                    uint32_t slot = atomicAdd(exCnt, 1u);
                    if (slot < NEX) {
                        exQ[2 * slot]     = (i4[m] << 16) | r;
                        exQ[2 * slot + 1] = (uint32_t)pr;
                    }
                }
            }
        }
    }
    __syncthreads();  // pD/pIdx/cnt reads done; exQ finalized; region reusable

    // ---- t prep: zero, pad, prArr writes, adopt extras, finish tk ----
    if (tid < NSUBT / 4) ((uint4*)cnt)[tid] = z4;
    if (tid < NHIST / 4) ((uint4*)hist)[tid] = z4;
    if (tid < 4) tD[KSEL + tid] = 0xFFFFFFFFu;
    uint32_t nEx = *exCnt; if (nEx > NEX) nEx = NEX;
    uint32_t exR = KSEL, exPr = 0, exI = 0;
    if ((uint32_t)tid < nEx) {
        uint32_t rec = exQ[2 * tid];
        exR = rec & 0xFFFFu; exI = rec >> 16; exPr = exQ[2 * tid + 1];
    }
    float exV = ((uint32_t)tid < nEx) ? targets[(size_t)exI * NCOLS + c] : 0.0f;
#pragma unroll
    for (int j = 0; j < 4; ++j) {
        uint32_t r = rp4[j] & 0xFFFFu;
        if (r < KSEL) prArr[r] = (uint16_t)(rp4[j] >> 16);
        tk4[j] = orderable(__float_as_uint(tv[j]));
    }
    if (exR < KSEL) prArr[exR] = (uint16_t)exPr;
    uint32_t exK = orderable(__float_as_uint(exV));
    __syncthreads();

    // ---- t: histogram (selected only: 4 low slots + extra) ----
#pragma unroll
    for (int j = 0; j < 4; ++j)
        if ((rp4[j] & 0xFFFFu) < KSEL) atomicAdd(&hist[tk4[j] >> 21], 1u);
    if (exR < KSEL) atomicAdd(&hist[exK >> 21], 1u);
    __syncthreads();

    alloc_subbins(hist, wtot, tid, lane, wave);

    uint32_t tpk[4] = {0,0,0,0}, exPk = 0;
#pragma unroll
    for (int j = 0; j < 4; ++j)
        if ((rp4[j] & 0xFFFFu) < KSEL) {
            uint32_t s = bin_of(tk4[j], hist);
            uint32_t sq = atomicAdd(&cnt[s], 1u);
            tpk[j] = s | (sq << 16);
        }
    if (exR < KSEL) {
        uint32_t s = bin_of(exK, hist);
        uint32_t sq = atomicAdd(&cnt[s], 1u);
        exPk = s | (sq << 16);
    }
    __syncthreads();

    scan_cnt(cnt, wtot, tid, lane, wave, NSUBT / 4);

#pragma unroll
    for (int j = 0; j < 4; ++j) {
        uint32_t r = rp4[j] & 0xFFFFu;
        if (r < KSEL) {
            uint32_t s = tpk[j] & 0xFFFu;
            uint32_t dst = cnt[s] + (tpk[j] >> 16);
            tD[dst]   = tk4[j];
            tPos[dst] = (uint16_t)r;
        }
    }
    if (exR < KSEL) {
        uint32_t s = exPk & 0xFFFu;
        uint32_t dst = cnt[s] + (exPk >> 16);
        tD[dst]   = exK;
        tPos[dst] = (uint16_t)exR;
    }
    __syncthreads();

    // ---- t: shared-span rank scan + dot (positions tid*4 .. tid*4+3) ----
    long long S = 0;
    {
        uint4 kv4 = ((const uint4*)tD)[tid];
        uint2 pp  = ((const uint2*)tPos)[tid];
        uint32_t kk[4] = {kv4.x, kv4.y, kv4.z, kv4.w};
        uint32_t pq[4] = {pp.x & 0xFFFFu, pp.x >> 16, pp.y & 0xFFFFu, pp.y >> 16};
        uint32_t A2 = cnt[bin_of(kk[0], hist)];
        uint32_t B2 = cnt[bin_of(kk[3], hist) + 1];
        uint32_t a0 = A2 & ~3u;
        uint32_t less[4] = {0,0,0,0}, eqc[4] = {0,0,0,0};
        for (uint32_t q = a0; q < B2; q += 4) {
            uint4 kv = ((const uint4*)tD)[q >> 2];
#pragma unroll
            for (int m = 0; m < 4; ++m) {
                uint32_t kl = kk[m];
                less[m] += (kv.x < kl) + (kv.y < kl) + (kv.z < kl) + (kv.w < kl);
                eqc[m]  += (kv.x == kl) + (kv.y == kl) + (kv.z == kl) + (kv.w == kl);
            }
        }
#pragma unroll
        for (int m = 0; m < 4; ++m) {
            uint32_t eqb = 0;
            if (eqc[m] > 1) {
                for (uint32_t q = A2; q < B2; ++q)
                    if (tD[q] == kk[m]) eqb += ((uint32_t)tPos[q] < pq[m]);
            }
            uint32_t tr = a0 + less[m] + eqb;
            S += (long long)prArr[pq[m]] * (long long)tr;
        }
    }

    // ---- reduce + epilogue (identical math to verified kernels) ----
#pragma unroll
    for (int off = 32; off > 0; off >>= 1)
        S += __shfl_down(S, off, 64);
    if (lane == 0) atomicAdd(sumAcc, (unsigned long long)S);
    __syncthreads();

    if (tid == 0) {
        double Sd = (double)(long long)(*sumAcc);
        double mean = (double)(KSEL - 1) * 0.5;
        double cov = Sd / (double)KSEL - mean * mean;
        double stdprod = (double)KSEL * (double)(KSEL + 1) / 12.0;
        out[c] = (float)(cov / (stdprod + 1e-8));
    }
}

extern "C" void kernel_launch(void* const* d_in, const int* in_sizes, int n_in,
                              void* d_out, int out_size, void* d_ws, size_t ws_size,
                              hipStream_t stream) {
    const float* preds   = (const float*)d_in[0];
    const float* targets = (const float*)d_in[1];
    float* out = (float*)d_out;
    hipLaunchKernelGGL(rank_ic_kernel, dim3(NCOLS), dim3(THREADS), 0, stream,
                       preds, targets, out);
}